// Round 16
// baseline (48.516 us; speedup 1.0000x reference)
//
#include <hip/hip_runtime.h>
#include <hip/hip_bf16.h>
#include <math.h>

#define LA 1536
#define LS 512
#define LT 2048
#define CC 256
#define NH 4
#define DKH 64
#define NB 4
#define NT (LT / 64)
#define NTA (LA / 64)   // 24 audio tiles
#define SZ ((size_t)NB * LT * CC)   // 2,097,152

typedef _Float16 f16;
typedef __attribute__((ext_vector_type(8))) _Float16 f16x8;
typedef __attribute__((ext_vector_type(4))) _Float16 f16x4;
typedef __attribute__((ext_vector_type(4))) float f32x4;

__device__ inline f16x8 cvt8(const float4 a, const float4 b) {
    f16x8 h;
    h[0] = (_Float16)a.x; h[1] = (_Float16)a.y; h[2] = (_Float16)a.z; h[3] = (_Float16)a.w;
    h[4] = (_Float16)b.x; h[5] = (_Float16)b.y; h[6] = (_Float16)b.z; h[7] = (_Float16)b.w;
    return h;
}

// ---------------------------------------------------------------------------
// Kernel 0: one-shot fp32 -> f16 conversion of X (concat audio|text) and the
// four weight matrices. Removes the 12x re-convert in qkv (X was re-loaded
// and re-converted once per n-tile) and the per-block Wo convert in out.
// 12.6 MB read + 4.7 MB written, memory-bound, ~2 us.
// ---------------------------------------------------------------------------
__global__ __launch_bounds__(256) void prep_f16(
    const float* __restrict__ audio, const float* __restrict__ text,
    const float* __restrict__ Wq, const float* __restrict__ Wk,
    const float* __restrict__ Wv, const float* __restrict__ Wo,
    f16* __restrict__ Xh, f16* __restrict__ Wh)   // Wh: 4 x 65536
{
    const int t = blockIdx.x * 256 + threadIdx.x;   // 294912 threads total
    const size_t i8 = (size_t)t * 8;
    if (i8 < SZ) {                                  // X region: [b][l][c]
        const int xi = (int)i8;
        const int c  = xi & 255;
        const int l  = (xi >> 8) & 2047;
        const int b  = xi >> 19;
        const float* src = (l < LA)
            ? (audio + ((size_t)b * LA + l) * CC + c)
            : (text  + ((size_t)b * LS + (l - LA)) * CC + c);
        const float4 x0 = *(const float4*)src;
        const float4 x1 = *(const float4*)(src + 4);
        *(f16x8*)(Xh + i8) = cvt8(x0, x1);
    } else {                                        // weights region
        const int wi = (int)(i8 - SZ);              // 0 .. 262143
        const int mat = wi >> 16;
        const int off = wi & 65535;
        const float* W = (mat == 0) ? Wq : (mat == 1) ? Wk : (mat == 2) ? Wv : Wo;
        const float4 x0 = *(const float4*)(W + off);
        const float4 x1 = *(const float4*)(W + off + 4);
        *(f16x8*)(Wh + wi) = cvt8(x0, x1);
    }
}

// ---------------------------------------------------------------------------
// Kernel 1: fused QKV projection, fp16 MFMA, fp32 accumulate.
// R4/R15 structure; staging is now a PURE f16 copy from Xh / Wh (no cvt, no
// audio/text branch, half the staging load bytes).
// Q,K row-major f16; V transposed Vt[(b*NH+h)*DKH+d][l] via LDS transpose.
// ---------------------------------------------------------------------------
__global__ __launch_bounds__(256) void qkv_mfma(
    const f16* __restrict__ Xh, const f16* __restrict__ Wh,
    const float* __restrict__ bq, const float* __restrict__ bk,
    const float* __restrict__ bv,
    f16* __restrict__ Qh, f16* __restrict__ Kh, f16* __restrict__ Vth)
{
    __shared__ f16 smem[128 * 64 + 64 * 64];   // As | Bs ; reused as Ts for V
    f16* As = smem;
    f16* Bs = smem + 128 * 64;

    const int tid = threadIdx.x;
    const int w = tid >> 6, l = tid & 63;
    const int g = l >> 4, r = l & 15;

    const int m0 = blockIdx.x * 128;
    const int n0 = blockIdx.y * 64;
    const int mat = n0 >> 8;          // 0=Q 1=K 2=V
    const int ch0 = n0 & 255;

    const f16*  Wmat = Wh + (size_t)mat * 65536;
    const float* bias = (mat == 0) ? bq : (mat == 1) ? bk : bv;

    f32x4 acc[2][4] = {};

    for (int k0 = 0; k0 < CC; k0 += 64) {
        #pragma unroll
        for (int m = 0; m < 4; ++m) {             // A: 128 rows x 8 chunks (copy)
            const int idx = m * 256 + tid;
            const int row = idx >> 3, c = idx & 7;
            *(f16x8*)(As + row * 64 + ((c ^ (row & 7)) << 3)) =
                *(const f16x8*)(Xh + (size_t)(m0 + row) * CC + k0 + c * 8);
        }
        #pragma unroll
        for (int m = 0; m < 2; ++m) {             // B: 64 rows x 8 chunks (copy)
            const int idx = m * 256 + tid;
            const int row = idx >> 3, c = idx & 7;
            *(f16x8*)(Bs + row * 64 + ((c ^ (row & 7)) << 3)) =
                *(const f16x8*)(Wmat + (size_t)(ch0 + row) * CC + k0 + c * 8);
        }
        __syncthreads();
        #pragma unroll
        for (int kc = 0; kc < 2; ++kc) {
            f16x8 af[2];
            #pragma unroll
            for (int i = 0; i < 2; ++i) {
                const int row = w * 32 + i * 16 + r;
                const int c = kc * 4 + g;
                af[i] = *(const f16x8*)(As + row * 64 + ((c ^ (row & 7)) << 3));
            }
            f16x8 bf[4];
            #pragma unroll
            for (int j = 0; j < 4; ++j) {
                const int row = j * 16 + r;
                const int c = kc * 4 + g;
                bf[j] = *(const f16x8*)(Bs + row * 64 + ((c ^ (row & 7)) << 3));
            }
            #pragma unroll
            for (int i = 0; i < 2; ++i)
                #pragma unroll
                for (int j = 0; j < 4; ++j)
                    acc[i][j] = __builtin_amdgcn_mfma_f32_16x16x32_f16(af[i], bf[j], acc[i][j], 0, 0, 0);
        }
        __syncthreads();
    }

    float bcol[4];
    #pragma unroll
    for (int j = 0; j < 4; ++j) bcol[j] = bias[ch0 + j * 16 + r];

    if (mat <= 1) {
        f16* Out = (mat == 0) ? Qh : Kh;
        #pragma unroll
        for (int i = 0; i < 2; ++i)
            #pragma unroll
            for (int e = 0; e < 4; ++e) {
                const int m = m0 + w * 32 + i * 16 + g * 4 + e;
                #pragma unroll
                for (int j = 0; j < 4; ++j)
                    Out[(size_t)m * CC + ch0 + j * 16 + r] = (_Float16)(acc[i][j][e] + bcol[j]);
            }
    } else {
        // V: stage C^T in LDS (Ts[64 n][136 m-pad]), then coalesced vec8 store.
        f16* Ts = smem;
        #pragma unroll
        for (int i = 0; i < 2; ++i)
            #pragma unroll
            for (int e = 0; e < 4; ++e) {
                const int ml = w * 32 + i * 16 + g * 4 + e;
                #pragma unroll
                for (int j = 0; j < 4; ++j)
                    Ts[(j * 16 + r) * 136 + ml] = (_Float16)(acc[i][j][e] + bcol[j]);
            }
        __syncthreads();
        const int b2 = m0 >> 11, l0m = m0 & 2047;
        #pragma unroll
        for (int u = 0; u < 4; ++u) {
            const int idx = u * 256 + tid;
            const int nl = idx >> 4, mc = idx & 15;
            const f16x8 vv = *(const f16x8*)(Ts + nl * 136 + mc * 8);
            const int nglob = ch0 + nl;
            const int hh = nglob >> 6, dd = nglob & 63;
            *(f16x8*)(Vth + ((size_t)((b2 * NH + hh) * DKH + dd)) * LT + l0m + mc * 8) = vv;
        }
    }
}

// ---------------------------------------------------------------------------
// Kernel 2: flash attention (R15 VERBATIM - proven best, frozen).
// R4 structure + XCD-aware block remap: flat 1-D grid of 512, cmb = flat & 15
// selects (b,h) so same-combo blocks share an XCD (FETCH 74 -> 38 MB).
// ---------------------------------------------------------------------------
__global__ __launch_bounds__(512) void attn_f16(
    const f16* __restrict__ Q, const f16* __restrict__ K,
    const f16* __restrict__ Vt,
    const int* __restrict__ slen, const int* __restrict__ tlen,
    f16* __restrict__ AO)
{
    __shared__ f16 Ks[2][4096];       // [group][key*64+d'], swizzled
    __shared__ f16 Vts[2][4096];      // [group][d*64+key'], swizzled
    __shared__ f16 Ps[8][16 * 72];    // per-wave P
    __shared__ float Oc[4][1024];     // group-1 o
    __shared__ float ML[2][64][2];    // [group][q_local][m,l]

    const int tid = threadIdx.x;
    const int w = tid >> 6, l = tid & 63;
    const int gid = w >> 2, wg = w & 3;
    const int g = l >> 4, r = l & 15;
    const int tg = tid & 255;

    // ---- XCD-aware remap: combo fastest, q-tile slowest
    const int flat = blockIdx.x;
    const int cmb  = flat & 15;
    const int q0   = (flat >> 4) * 64;
    const int h    = cmb & 3;
    const int b    = cmb >> 2;

    const int ilen = slen[b];
    const int kcap = LA + tlen[b];
    const int nskip = ilen >> 6;
    int ntskip = 0;
    if (q0 >= LA) {
        const int skipmax = min(q0 - 63, kcap - 64);
        const int d = skipmax - LA;
        ntskip = (d < 0) ? 0 : ((d >> 6) + 1);
    }
    const int nAudio = NTA - nskip;
    const int nProc  = nAudio + (NT - NTA) - ntskip;
    const int nIter  = (nProc + 1) >> 1;

    const int qrow = q0 + 16 * wg + r;

    f16x8 qf[2];
    #pragma unroll
    for (int ch = 0; ch < 2; ++ch) {
        f16x8 q8 = *(const f16x8*)(Q + ((size_t)(b * LT) + qrow) * CC + h * DKH + ch * 32 + g * 8);
        #pragma unroll
        for (int e = 0; e < 8; ++e) q8[e] = q8[e] * (_Float16)0.125f;
        qf[ch] = q8;
    }

    const int srow0 = tg >> 3, scc = tg & 7;
    const int srow1 = srow0 + 32;
    const int sdst0 = srow0 * 64 + ((scc ^ (srow0 & 7)) << 3);
    const int sdst1 = srow1 * 64 + ((scc ^ (srow1 & 7)) << 3);

    #define TILE_OF(p) ((p) < nAudio ? (nskip + (p)) : (NTA + ntskip + ((p) - nAudio)))

    {   // prologue
        const int k0 = TILE_OF(gid) * 64;
        *(f16x8*)(Ks[gid] + sdst0)  = *(const f16x8*)(K  + ((size_t)(b * LT) + k0 + srow0) * CC + h * DKH + scc * 8);
        *(f16x8*)(Vts[gid] + sdst0) = *(const f16x8*)(Vt + ((size_t)((b * NH + h) * DKH) + srow0) * LT + k0 + scc * 8);
        *(f16x8*)(Ks[gid] + sdst1)  = *(const f16x8*)(K  + ((size_t)(b * LT) + k0 + srow1) * CC + h * DKH + scc * 8);
        *(f16x8*)(Vts[gid] + sdst1) = *(const f16x8*)(Vt + ((size_t)((b * NH + h) * DKH) + srow1) * LT + k0 + scc * 8);
    }

    float m_run = -1e30f, l_run = 0.0f;
    f32x4 o[4] = {};

    for (int i = 0; i < nIter; ++i) {
        __syncthreads();                       // A: LDS tiles visible
        const int pcur = 2 * i + gid;
        const bool curV = pcur < nProc;
        const bool nxtV = (pcur + 2) < nProc;

        f16x8 kr0, vr0, kr1, vr1;
        if (nxtV) {
            const int kn = TILE_OF(pcur + 2) * 64;
            kr0 = *(const f16x8*)(K  + ((size_t)(b * LT) + kn + srow0) * CC + h * DKH + scc * 8);
            vr0 = *(const f16x8*)(Vt + ((size_t)((b * NH + h) * DKH) + srow0) * LT + kn + scc * 8);
            kr1 = *(const f16x8*)(K  + ((size_t)(b * LT) + kn + srow1) * CC + h * DKH + scc * 8);
            vr1 = *(const f16x8*)(Vt + ((size_t)((b * NH + h) * DKH) + srow1) * LT + kn + scc * 8);
        }

        if (curV) {
            const int kt = TILE_OF(pcur);
            const int k0 = kt * 64;

            f32x4 sacc[4] = {};
            #pragma unroll
            for (int s = 0; s < 4; ++s) {
                const int row = 16 * s + r;
                #pragma unroll
                for (int ch = 0; ch < 2; ++ch) {
                    const f16x8 a = *(const f16x8*)(Ks[gid] + row * 64 + ((((ch * 4 + g) ^ (row & 7)) & 7) << 3));
                    sacc[s] = __builtin_amdgcn_mfma_f32_16x16x32_f16(a, qf[ch], sacc[s], 0, 0, 0);
                }
            }

            const int mode = (kt < NTA) ? ((k0 >= ilen) ? 0 : 1)
                                        : ((q0 < LA) ? 0 : 2);
            float sv[16];
            if (mode == 0) {
                #pragma unroll
                for (int s = 0; s < 4; ++s)
                    #pragma unroll
                    for (int e = 0; e < 4; ++e) sv[s * 4 + e] = sacc[s][e];
            } else if (mode == 1) {
                #pragma unroll
                for (int s = 0; s < 4; ++s)
                    #pragma unroll
                    for (int e = 0; e < 4; ++e) {
                        const int kk = k0 + 16 * s + 4 * g + e;
                        sv[s * 4 + e] = (kk >= ilen) ? sacc[s][e] : -INFINITY;
                    }
            } else {
                #pragma unroll
                for (int s = 0; s < 4; ++s)
                    #pragma unroll
                    for (int e = 0; e < 4; ++e) {
                        const int kk = k0 + 16 * s + 4 * g + e;
                        sv[s * 4 + e] = (kk > qrow || kk >= kcap) ? sacc[s][e] : -INFINITY;
                    }
            }

            float mloc = -1e30f;
            #pragma unroll
            for (int u = 0; u < 16; ++u) mloc = fmaxf(mloc, sv[u]);
            mloc = fmaxf(mloc, __shfl_xor(mloc, 16));
            mloc = fmaxf(mloc, __shfl_xor(mloc, 32));
            const float m_new = fmaxf(m_run, mloc);

            float ssum = 0.0f;
            f16x4 ph[4];
            #pragma unroll
            for (int s = 0; s < 4; ++s)
                #pragma unroll
                for (int e = 0; e < 4; ++e) {
                    const float p = __expf(sv[s * 4 + e] - m_new);
                    ph[s][e] = (_Float16)p;
                    ssum += p;
                }
            ssum += __shfl_xor(ssum, 16);
            ssum += __shfl_xor(ssum, 32);
            const float sc = __expf(m_run - m_new);
            l_run = l_run * sc + ssum;
            m_run = m_new;

            #pragma unroll
            for (int s = 0; s < 4; ++s)
                *(f16x4*)(&Ps[w][0] + r * 72 + 16 * s + 4 * g) = ph[s];

            #pragma unroll
            for (int e = 0; e < 4; ++e) {
                const float scr = __shfl(sc, 4 * g + e);
                #pragma unroll
                for (int dsb = 0; dsb < 4; ++dsb) o[dsb][e] *= scr;
            }

            #pragma unroll
            for (int ch = 0; ch < 2; ++ch) {
                const f16x8 a = *(const f16x8*)(&Ps[w][0] + r * 72 + ch * 32 + g * 8);
                #pragma unroll
                for (int dsb = 0; dsb < 4; ++dsb) {
                    const int vrow = 16 * dsb + r;
                    const f16x8 bf = *(const f16x8*)(Vts[gid] + vrow * 64 + ((((ch * 4 + g) ^ (vrow & 7)) & 7) << 3));
                    o[dsb] = __builtin_amdgcn_mfma_f32_16x16x32_f16(a, bf, o[dsb], 0, 0, 0);
                }
            }
        }

        __syncthreads();                       // B: group's LDS reads done
        if (nxtV) {
            *(f16x8*)(Ks[gid] + sdst0)  = kr0;
            *(f16x8*)(Vts[gid] + sdst0) = vr0;
            *(f16x8*)(Ks[gid] + sdst1)  = kr1;
            *(f16x8*)(Vts[gid] + sdst1) = vr1;
        }
    }

    // ---- combine the two groups' partials
    if (g == 0) {
        ML[gid][16 * wg + r][0] = m_run;
        ML[gid][16 * wg + r][1] = l_run;
    }
    if (gid == 1) {
        #pragma unroll
        for (int dsb = 0; dsb < 4; ++dsb)
            *(f32x4*)&Oc[wg][dsb * 256 + (g * 16 + r) * 4] = o[dsb];
    }
    __syncthreads();

    if (gid == 0) {
        #pragma unroll
        for (int e = 0; e < 4; ++e) {
            const int qloc = 16 * wg + 4 * g + e;
            const float m0v = ML[0][qloc][0], l0v = ML[0][qloc][1];
            const float m1v = ML[1][qloc][0], l1v = ML[1][qloc][1];
            const float mt = fmaxf(m0v, m1v);
            const float c0 = __expf(m0v - mt);
            const float c1 = __expf(m1v - mt);
            const float inv = 1.0f / (l0v * c0 + l1v * c1);
            const int qq = q0 + qloc;
            #pragma unroll
            for (int dsb = 0; dsb < 4; ++dsb) {
                const float of = (o[dsb][e] * c0 + Oc[wg][dsb * 256 + (g * 16 + r) * 4 + e] * c1) * inv;
                AO[((size_t)(b * LT) + qq) * CC + h * DKH + 16 * dsb + r] = (_Float16)of;
            }
        }
    }
    #undef TILE_OF
}

// ---------------------------------------------------------------------------
// Kernel 3: output projection, fp16 MFMA; Wo read pre-converted (Woh).
// ---------------------------------------------------------------------------
__global__ __launch_bounds__(256) void out_mfma(
    const f16* __restrict__ X, const f16* __restrict__ Woh,
    const float* __restrict__ bo, float* __restrict__ Out)
{
    __shared__ f16 As[128 * 64];
    __shared__ f16 Bs[64 * 64];

    const int tid = threadIdx.x;
    const int w = tid >> 6, l = tid & 63;
    const int g = l >> 4, r = l & 15;

    const int m0 = blockIdx.x * 128;
    const int n0 = blockIdx.y * 64;

    f32x4 acc[2][4] = {};

    for (int k0 = 0; k0 < CC; k0 += 64) {
        #pragma unroll
        for (int m = 0; m < 4; ++m) {
            const int idx = m * 256 + tid;
            const int row = idx >> 3, c = idx & 7;
            *(f16x8*)(As + row * 64 + ((c ^ (row & 7)) << 3)) =
                *(const f16x8*)(X + (size_t)(m0 + row) * CC + k0 + c * 8);
        }
        #pragma unroll
        for (int m = 0; m < 2; ++m) {
            const int idx = m * 256 + tid;
            const int row = idx >> 3, c = idx & 7;
            *(f16x8*)(Bs + row * 64 + ((c ^ (row & 7)) << 3)) =
                *(const f16x8*)(Woh + (size_t)(n0 + row) * CC + k0 + c * 8);
        }
        __syncthreads();
        #pragma unroll
        for (int kc = 0; kc < 2; ++kc) {
            f16x8 af[2];
            #pragma unroll
            for (int i = 0; i < 2; ++i) {
                const int row = w * 32 + i * 16 + r;
                const int c = kc * 4 + g;
                af[i] = *(const f16x8*)(As + row * 64 + ((c ^ (row & 7)) << 3));
            }
            f16x8 bf[4];
            #pragma unroll
            for (int j = 0; j < 4; ++j) {
                const int row = j * 16 + r;
                const int c = kc * 4 + g;
                bf[j] = *(const f16x8*)(Bs + row * 64 + ((c ^ (row & 7)) << 3));
            }
            #pragma unroll
            for (int i = 0; i < 2; ++i)
                #pragma unroll
                for (int j = 0; j < 4; ++j)
                    acc[i][j] = __builtin_amdgcn_mfma_f32_16x16x32_f16(af[i], bf[j], acc[i][j], 0, 0, 0);
        }
        __syncthreads();
    }

    float bcol[4];
    #pragma unroll
    for (int j = 0; j < 4; ++j) bcol[j] = bo[n0 + j * 16 + r];

    #pragma unroll
    for (int i = 0; i < 2; ++i)
        #pragma unroll
        for (int e = 0; e < 4; ++e) {
            const int m = m0 + w * 32 + i * 16 + g * 4 + e;
            #pragma unroll
            for (int j = 0; j < 4; ++j)
                Out[(size_t)m * CC + n0 + j * 16 + r] = acc[i][j][e] + bcol[j];
        }
}

// ---------------------------------------------------------------------------
extern "C" void kernel_launch(void* const* d_in, const int* in_sizes, int n_in,
                              void* d_out, int out_size, void* d_ws, size_t ws_size,
                              hipStream_t stream)
{
    const float* audio = (const float*)d_in[0];
    const float* text  = (const float*)d_in[1];
    const int*   slen  = (const int*)d_in[2];
    const int*   tlen  = (const int*)d_in[3];
    const float* Wq = (const float*)d_in[4];
    const float* bq = (const float*)d_in[5];
    const float* Wk = (const float*)d_in[6];
    const float* bk = (const float*)d_in[7];
    const float* Wv = (const float*)d_in[8];
    const float* bv = (const float*)d_in[9];
    const float* Wo = (const float*)d_in[10];
    const float* bo = (const float*)d_in[11];
    float* out = (float*)d_out;

    // ws: Qh,Kh,Vth,AOh,Xh (SZ f16 each) | Wh (4*65536 f16) = ~21.5 MB
    f16* Qh  = (f16*)d_ws;
    f16* Kh  = Qh + SZ;
    f16* Vth = Kh + SZ;
    f16* AOh = Vth + SZ;
    f16* Xh  = AOh + SZ;
    f16* Wh  = Xh + SZ;

    // threads: (SZ + 4*65536)/8 = 294912 -> 1152 blocks
    prep_f16<<<dim3(1152), 256, 0, stream>>>(audio, text, Wq, Wk, Wv, Wo, Xh, Wh);
    qkv_mfma<<<dim3(64, 12), 256, 0, stream>>>(Xh, Wh, bq, bk, bv, Qh, Kh, Vth);
    attn_f16<<<dim3(512), 512, 0, stream>>>(Qh, Kh, Vth, slen, tlen, AOh);
    out_mfma<<<dim3(64, 4), 256, 0, stream>>>(AOh, Wh + 3 * 65536, bo, out);
}

// Round 17
// 48.088 us; speedup vs baseline: 1.0089x; 1.0089x over previous
//
#include <hip/hip_runtime.h>
#include <hip/hip_bf16.h>
#include <math.h>

#define LA 1536
#define LS 512
#define LT 2048
#define CC 256
#define NH 4
#define DKH 64
#define NB 4
#define NT (LT / 64)
#define NTA (LA / 64)   // 24 audio tiles

typedef _Float16 f16;
typedef __attribute__((ext_vector_type(8))) _Float16 f16x8;
typedef __attribute__((ext_vector_type(4))) _Float16 f16x4;
typedef __attribute__((ext_vector_type(4))) float f32x4;

__device__ inline f16x8 cvt8(const float4 a, const float4 b) {
    f16x8 h;
    h[0] = (_Float16)a.x; h[1] = (_Float16)a.y; h[2] = (_Float16)a.z; h[3] = (_Float16)a.w;
    h[4] = (_Float16)b.x; h[5] = (_Float16)b.y; h[6] = (_Float16)b.z; h[7] = (_Float16)b.w;
    return h;
}

// ---------------------------------------------------------------------------
// Kernel 1: fused QKV projection, fp16 MFMA, fp32 accumulate.
// Q,K row-major f16; V transposed Vt[(b*NH+h)*DKH+d][l] via LDS transpose.
// ---------------------------------------------------------------------------
__global__ __launch_bounds__(256) void qkv_mfma(
    const float* __restrict__ audio, const float* __restrict__ text,
    const float* __restrict__ Wq, const float* __restrict__ bq,
    const float* __restrict__ Wk, const float* __restrict__ bk,
    const float* __restrict__ Wv, const float* __restrict__ bv,
    f16* __restrict__ Qh, f16* __restrict__ Kh, f16* __restrict__ Vth)
{
    __shared__ f16 smem[128 * 64 + 64 * 64];   // As | Bs ; reused as Ts for V
    f16* As = smem;
    f16* Bs = smem + 128 * 64;

    const int tid = threadIdx.x;
    const int w = tid >> 6, l = tid & 63;
    const int g = l >> 4, r = l & 15;

    const int m0 = blockIdx.x * 128;
    const int n0 = blockIdx.y * 64;
    const int mat = n0 >> 8;          // 0=Q 1=K 2=V
    const int ch0 = n0 & 255;

    const float* W    = (mat == 0) ? Wq : (mat == 1) ? Wk : Wv;
    const float* bias = (mat == 0) ? bq : (mat == 1) ? bk : bv;

    const int b  = m0 >> 11;
    const int l0 = m0 & 2047;         // 1536 % 128 == 0 -> clean split

    f32x4 acc[2][4] = {};

    for (int k0 = 0; k0 < CC; k0 += 64) {
        #pragma unroll
        for (int m = 0; m < 4; ++m) {
            const int idx = m * 256 + tid;
            const int row = idx >> 3, c = idx & 7;
            const int lrow = l0 + row;
            const float* src = (lrow < LA)
                ? (audio + ((size_t)b * LA + lrow) * CC + k0 + c * 8)
                : (text  + ((size_t)b * LS + (lrow - LA)) * CC + k0 + c * 8);
            const float4 x0 = *(const float4*)src;
            const float4 x1 = *(const float4*)(src + 4);
            *(f16x8*)(As + row * 64 + ((c ^ (row & 7)) << 3)) = cvt8(x0, x1);
        }
        #pragma unroll
        for (int m = 0; m < 2; ++m) {
            const int idx = m * 256 + tid;
            const int row = idx >> 3, c = idx & 7;
            const float* src = W + (size_t)(ch0 + row) * CC + k0 + c * 8;
            const float4 x0 = *(const float4*)src;
            const float4 x1 = *(const float4*)(src + 4);
            *(f16x8*)(Bs + row * 64 + ((c ^ (row & 7)) << 3)) = cvt8(x0, x1);
        }
        __syncthreads();
        #pragma unroll
        for (int kc = 0; kc < 2; ++kc) {
            f16x8 af[2];
            #pragma unroll
            for (int i = 0; i < 2; ++i) {
                const int row = w * 32 + i * 16 + r;
                const int c = kc * 4 + g;
                af[i] = *(const f16x8*)(As + row * 64 + ((c ^ (row & 7)) << 3));
            }
            f16x8 bf[4];
            #pragma unroll
            for (int j = 0; j < 4; ++j) {
                const int row = j * 16 + r;
                const int c = kc * 4 + g;
                bf[j] = *(const f16x8*)(Bs + row * 64 + ((c ^ (row & 7)) << 3));
            }
            #pragma unroll
            for (int i = 0; i < 2; ++i)
                #pragma unroll
                for (int j = 0; j < 4; ++j)
                    acc[i][j] = __builtin_amdgcn_mfma_f32_16x16x32_f16(af[i], bf[j], acc[i][j], 0, 0, 0);
        }
        __syncthreads();
    }

    float bcol[4];
    #pragma unroll
    for (int j = 0; j < 4; ++j) bcol[j] = bias[ch0 + j * 16 + r];

    if (mat <= 1) {
        f16* Out = (mat == 0) ? Qh : Kh;
        #pragma unroll
        for (int i = 0; i < 2; ++i)
            #pragma unroll
            for (int e = 0; e < 4; ++e) {
                const int m = m0 + w * 32 + i * 16 + g * 4 + e;
                #pragma unroll
                for (int j = 0; j < 4; ++j)
                    Out[(size_t)m * CC + ch0 + j * 16 + r] = (_Float16)(acc[i][j][e] + bcol[j]);
            }
    } else {
        // V: stage C^T in LDS (Ts[64 n][136 m-pad]), then coalesced vec8 store.
        f16* Ts = smem;
        #pragma unroll
        for (int i = 0; i < 2; ++i)
            #pragma unroll
            for (int e = 0; e < 4; ++e) {
                const int ml = w * 32 + i * 16 + g * 4 + e;
                #pragma unroll
                for (int j = 0; j < 4; ++j)
                    Ts[(j * 16 + r) * 136 + ml] = (_Float16)(acc[i][j][e] + bcol[j]);
            }
        __syncthreads();
        const int b2 = m0 >> 11, l0m = m0 & 2047;
        #pragma unroll
        for (int u = 0; u < 4; ++u) {
            const int idx = u * 256 + tid;
            const int nl = idx >> 4, mc = idx & 15;
            const f16x8 vv = *(const f16x8*)(Ts + nl * 136 + mc * 8);
            const int nglob = ch0 + nl;
            const int hh = nglob >> 6, dd = nglob & 63;
            *(f16x8*)(Vth + ((size_t)((b2 * NH + hh) * DKH + dd)) * LT + l0m + mc * 8) = vv;
        }
    }
}

// ---------------------------------------------------------------------------
// Kernel 2: flash attention (R4 structure) + XCD-AWARE BLOCK REMAP (T1).
// Flat 1-D grid of 512: cmb = flat & 15 selects (b,h), q-tile = flat >> 4.
// Under round-robin XCD dispatch (d % 8), all 32 q-blocks of one (b,h) land
// on ONE XCD -> 512 KB K/V stays L2-resident (measured FETCH 74 -> 38 MB).
// ---------------------------------------------------------------------------
__global__ __launch_bounds__(512) void attn_f16(
    const f16* __restrict__ Q, const f16* __restrict__ K,
    const f16* __restrict__ Vt,
    const int* __restrict__ slen, const int* __restrict__ tlen,
    f16* __restrict__ AO)
{
    __shared__ f16 Ks[2][4096];       // [group][key*64+d'], swizzled
    __shared__ f16 Vts[2][4096];      // [group][d*64+key'], swizzled
    __shared__ f16 Ps[8][16 * 72];    // per-wave P
    __shared__ float Oc[4][1024];     // group-1 o
    __shared__ float ML[2][64][2];    // [group][q_local][m,l]

    const int tid = threadIdx.x;
    const int w = tid >> 6, l = tid & 63;
    const int gid = w >> 2, wg = w & 3;
    const int g = l >> 4, r = l & 15;
    const int tg = tid & 255;

    const int flat = blockIdx.x;
    const int cmb  = flat & 15;
    const int q0   = (flat >> 4) * 64;
    const int h    = cmb & 3;
    const int b    = cmb >> 2;

    const int ilen = slen[b];
    const int kcap = LA + tlen[b];
    const int nskip = ilen >> 6;
    int ntskip = 0;
    if (q0 >= LA) {
        const int skipmax = min(q0 - 63, kcap - 64);
        const int d = skipmax - LA;
        ntskip = (d < 0) ? 0 : ((d >> 6) + 1);
    }
    const int nAudio = NTA - nskip;
    const int nProc  = nAudio + (NT - NTA) - ntskip;
    const int nIter  = (nProc + 1) >> 1;

    const int qrow = q0 + 16 * wg + r;

    f16x8 qf[2];
    #pragma unroll
    for (int ch = 0; ch < 2; ++ch) {
        f16x8 q8 = *(const f16x8*)(Q + ((size_t)(b * LT) + qrow) * CC + h * DKH + ch * 32 + g * 8);
        #pragma unroll
        for (int e = 0; e < 8; ++e) q8[e] = q8[e] * (_Float16)0.125f;
        qf[ch] = q8;
    }

    const int srow0 = tg >> 3, scc = tg & 7;
    const int srow1 = srow0 + 32;
    const int sdst0 = srow0 * 64 + ((scc ^ (srow0 & 7)) << 3);
    const int sdst1 = srow1 * 64 + ((scc ^ (srow1 & 7)) << 3);

    #define TILE_OF(p) ((p) < nAudio ? (nskip + (p)) : (NTA + ntskip + ((p) - nAudio)))

    {   // prologue
        const int k0 = TILE_OF(gid) * 64;
        *(f16x8*)(Ks[gid] + sdst0)  = *(const f16x8*)(K  + ((size_t)(b * LT) + k0 + srow0) * CC + h * DKH + scc * 8);
        *(f16x8*)(Vts[gid] + sdst0) = *(const f16x8*)(Vt + ((size_t)((b * NH + h) * DKH) + srow0) * LT + k0 + scc * 8);
        *(f16x8*)(Ks[gid] + sdst1)  = *(const f16x8*)(K  + ((size_t)(b * LT) + k0 + srow1) * CC + h * DKH + scc * 8);
        *(f16x8*)(Vts[gid] + sdst1) = *(const f16x8*)(Vt + ((size_t)((b * NH + h) * DKH) + srow1) * LT + k0 + scc * 8);
    }

    float m_run = -1e30f, l_run = 0.0f;
    f32x4 o[4] = {};

    for (int i = 0; i < nIter; ++i) {
        __syncthreads();                       // A: LDS tiles visible
        const int pcur = 2 * i + gid;
        const bool curV = pcur < nProc;
        const bool nxtV = (pcur + 2) < nProc;

        f16x8 kr0, vr0, kr1, vr1;
        if (nxtV) {
            const int kn = TILE_OF(pcur + 2) * 64;
            kr0 = *(const f16x8*)(K  + ((size_t)(b * LT) + kn + srow0) * CC + h * DKH + scc * 8);
            vr0 = *(const f16x8*)(Vt + ((size_t)((b * NH + h) * DKH) + srow0) * LT + kn + scc * 8);
            kr1 = *(const f16x8*)(K  + ((size_t)(b * LT) + kn + srow1) * CC + h * DKH + scc * 8);
            vr1 = *(const f16x8*)(Vt + ((size_t)((b * NH + h) * DKH) + srow1) * LT + kn + scc * 8);
        }

        if (curV) {
            const int kt = TILE_OF(pcur);
            const int k0 = kt * 64;

            f32x4 sacc[4] = {};
            #pragma unroll
            for (int s = 0; s < 4; ++s) {
                const int row = 16 * s + r;
                #pragma unroll
                for (int ch = 0; ch < 2; ++ch) {
                    const f16x8 a = *(const f16x8*)(Ks[gid] + row * 64 + ((((ch * 4 + g) ^ (row & 7)) & 7) << 3));
                    sacc[s] = __builtin_amdgcn_mfma_f32_16x16x32_f16(a, qf[ch], sacc[s], 0, 0, 0);
                }
            }

            const int mode = (kt < NTA) ? ((k0 >= ilen) ? 0 : 1)
                                        : ((q0 < LA) ? 0 : 2);
            float sv[16];
            if (mode == 0) {
                #pragma unroll
                for (int s = 0; s < 4; ++s)
                    #pragma unroll
                    for (int e = 0; e < 4; ++e) sv[s * 4 + e] = sacc[s][e];
            } else if (mode == 1) {
                #pragma unroll
                for (int s = 0; s < 4; ++s)
                    #pragma unroll
                    for (int e = 0; e < 4; ++e) {
                        const int kk = k0 + 16 * s + 4 * g + e;
                        sv[s * 4 + e] = (kk >= ilen) ? sacc[s][e] : -INFINITY;
                    }
            } else {
                #pragma unroll
                for (int s = 0; s < 4; ++s)
                    #pragma unroll
                    for (int e = 0; e < 4; ++e) {
                        const int kk = k0 + 16 * s + 4 * g + e;
                        sv[s * 4 + e] = (kk > qrow || kk >= kcap) ? sacc[s][e] : -INFINITY;
                    }
            }

            float mloc = -1e30f;
            #pragma unroll
            for (int u = 0; u < 16; ++u) mloc = fmaxf(mloc, sv[u]);
            mloc = fmaxf(mloc, __shfl_xor(mloc, 16));
            mloc = fmaxf(mloc, __shfl_xor(mloc, 32));
            const float m_new = fmaxf(m_run, mloc);

            float ssum = 0.0f;
            f16x4 ph[4];
            #pragma unroll
            for (int s = 0; s < 4; ++s)
                #pragma unroll
                for (int e = 0; e < 4; ++e) {
                    const float p = __expf(sv[s * 4 + e] - m_new);
                    ph[s][e] = (_Float16)p;
                    ssum += p;
                }
            ssum += __shfl_xor(ssum, 16);
            ssum += __shfl_xor(ssum, 32);
            const float sc = __expf(m_run - m_new);
            l_run = l_run * sc + ssum;
            m_run = m_new;

            #pragma unroll
            for (int s = 0; s < 4; ++s)
                *(f16x4*)(&Ps[w][0] + r * 72 + 16 * s + 4 * g) = ph[s];

            #pragma unroll
            for (int e = 0; e < 4; ++e) {
                const float scr = __shfl(sc, 4 * g + e);
                #pragma unroll
                for (int dsb = 0; dsb < 4; ++dsb) o[dsb][e] *= scr;
            }

            #pragma unroll
            for (int ch = 0; ch < 2; ++ch) {
                const f16x8 a = *(const f16x8*)(&Ps[w][0] + r * 72 + ch * 32 + g * 8);
                #pragma unroll
                for (int dsb = 0; dsb < 4; ++dsb) {
                    const int vrow = 16 * dsb + r;
                    const f16x8 bf = *(const f16x8*)(Vts[gid] + vrow * 64 + ((((ch * 4 + g) ^ (vrow & 7)) & 7) << 3));
                    o[dsb] = __builtin_amdgcn_mfma_f32_16x16x32_f16(a, bf, o[dsb], 0, 0, 0);
                }
            }
        }

        __syncthreads();                       // B: group's LDS reads done
        if (nxtV) {
            *(f16x8*)(Ks[gid] + sdst0)  = kr0;
            *(f16x8*)(Vts[gid] + sdst0) = vr0;
            *(f16x8*)(Ks[gid] + sdst1)  = kr1;
            *(f16x8*)(Vts[gid] + sdst1) = vr1;
        }
    }

    // ---- combine the two groups' partials
    if (g == 0) {
        ML[gid][16 * wg + r][0] = m_run;
        ML[gid][16 * wg + r][1] = l_run;
    }
    if (gid == 1) {
        #pragma unroll
        for (int dsb = 0; dsb < 4; ++dsb)
            *(f32x4*)&Oc[wg][dsb * 256 + (g * 16 + r) * 4] = o[dsb];
    }
    __syncthreads();

    if (gid == 0) {
        #pragma unroll
        for (int e = 0; e < 4; ++e) {
            const int qloc = 16 * wg + 4 * g + e;
            const float m0v = ML[0][qloc][0], l0v = ML[0][qloc][1];
            const float m1v = ML[1][qloc][0], l1v = ML[1][qloc][1];
            const float mt = fmaxf(m0v, m1v);
            const float c0 = __expf(m0v - mt);
            const float c1 = __expf(m1v - mt);
            const float inv = 1.0f / (l0v * c0 + l1v * c1);
            const int qq = q0 + qloc;
            #pragma unroll
            for (int dsb = 0; dsb < 4; ++dsb) {
                const float of = (o[dsb][e] * c0 + Oc[wg][dsb * 256 + (g * 16 + r) * 4 + e] * c1) * inv;
                AO[((size_t)(b * LT) + qq) * CC + h * DKH + 16 * dsb + r] = (_Float16)of;
            }
        }
    }
    #undef TILE_OF
}

// ---------------------------------------------------------------------------
// Kernel 3: output projection, fp16 MFMA (X already f16), fp32 out.
// ---------------------------------------------------------------------------
__global__ __launch_bounds__(256) void out_mfma(
    const f16* __restrict__ X, const float* __restrict__ Wo,
    const float* __restrict__ bo, float* __restrict__ Out)
{
    __shared__ f16 As[128 * 64];
    __shared__ f16 Bs[64 * 64];

    const int tid = threadIdx.x;
    const int w = tid >> 6, l = tid & 63;
    const int g = l >> 4, r = l & 15;

    const int m0 = blockIdx.x * 128;
    const int n0 = blockIdx.y * 64;

    f32x4 acc[2][4] = {};

    for (int k0 = 0; k0 < CC; k0 += 64) {
        #pragma unroll
        for (int m = 0; m < 4; ++m) {
            const int idx = m * 256 + tid;
            const int row = idx >> 3, c = idx & 7;
            *(f16x8*)(As + row * 64 + ((c ^ (row & 7)) << 3)) =
                *(const f16x8*)(X + (size_t)(m0 + row) * CC + k0 + c * 8);
        }
        #pragma unroll
        for (int m = 0; m < 2; ++m) {
            const int idx = m * 256 + tid;
            const int row = idx >> 3, c = idx & 7;
            const float* src = Wo + (size_t)(n0 + row) * CC + k0 + c * 8;
            const float4 x0 = *(const float4*)src;
            const float4 x1 = *(const float4*)(src + 4);
            *(f16x8*)(Bs + row * 64 + ((c ^ (row & 7)) << 3)) = cvt8(x0, x1);
        }
        __syncthreads();
        #pragma unroll
        for (int kc = 0; kc < 2; ++kc) {
            f16x8 af[2];
            #pragma unroll
            for (int i = 0; i < 2; ++i) {
                const int row = w * 32 + i * 16 + r;
                const int c = kc * 4 + g;
                af[i] = *(const f16x8*)(As + row * 64 + ((c ^ (row & 7)) << 3));
            }
            f16x8 bf[4];
            #pragma unroll
            for (int j = 0; j < 4; ++j) {
                const int row = j * 16 + r;
                const int c = kc * 4 + g;
                bf[j] = *(const f16x8*)(Bs + row * 64 + ((c ^ (row & 7)) << 3));
            }
            #pragma unroll
            for (int i = 0; i < 2; ++i)
                #pragma unroll
                for (int j = 0; j < 4; ++j)
                    acc[i][j] = __builtin_amdgcn_mfma_f32_16x16x32_f16(af[i], bf[j], acc[i][j], 0, 0, 0);
        }
        __syncthreads();
    }

    float bcol[4];
    #pragma unroll
    for (int j = 0; j < 4; ++j) bcol[j] = bo[n0 + j * 16 + r];

    #pragma unroll
    for (int i = 0; i < 2; ++i)
        #pragma unroll
        for (int e = 0; e < 4; ++e) {
            const int m = m0 + w * 32 + i * 16 + g * 4 + e;
            #pragma unroll
            for (int j = 0; j < 4; ++j)
                Out[(size_t)m * CC + n0 + j * 16 + r] = acc[i][j][e] + bcol[j];
        }
}

// ---------------------------------------------------------------------------
extern "C" void kernel_launch(void* const* d_in, const int* in_sizes, int n_in,
                              void* d_out, int out_size, void* d_ws, size_t ws_size,
                              hipStream_t stream)
{
    const float* audio = (const float*)d_in[0];
    const float* text  = (const float*)d_in[1];
    const int*   slen  = (const int*)d_in[2];
    const int*   tlen  = (const int*)d_in[3];
    const float* Wq = (const float*)d_in[4];
    const float* bq = (const float*)d_in[5];
    const float* Wk = (const float*)d_in[6];
    const float* bk = (const float*)d_in[7];
    const float* Wv = (const float*)d_in[8];
    const float* bv = (const float*)d_in[9];
    const float* Wo = (const float*)d_in[10];
    const float* bo = (const float*)d_in[11];
    float* out = (float*)d_out;

    const size_t SZ = (size_t)NB * LT * CC;
    f16* Qh  = (f16*)d_ws;
    f16* Kh  = Qh + SZ;
    f16* Vth = Kh + SZ;
    f16* AOh = Vth + SZ;

    qkv_mfma<<<dim3(64, 12), 256, 0, stream>>>(audio, text, Wq, bq, Wk, bk, Wv, bv,
                                               Qh, Kh, Vth);
    attn_f16<<<dim3(512), 512, 0, stream>>>(Qh, Kh, Vth, slen, tlen, AOh);
    out_mfma<<<dim3(64, 4), 256, 0, stream>>>(AOh, Wo, bo, out);
}